// Round 1
// 446.726 us; speedup vs baseline: 1.0152x; 1.0152x over previous
//
#include <hip/hip_runtime.h>

typedef __attribute__((ext_vector_type(2)))  __fp16   pk16x2;  // cvt_pkrtz result type
typedef __attribute__((ext_vector_type(4)))  float    f32x4;
typedef __attribute__((ext_vector_type(16))) float    f32x16;
typedef __attribute__((ext_vector_type(8)))  _Float16 f16x8;

#define NB 2
#define NN 384
#define NO 4
#define NC 128
#define NK 64
#define MTW 32              // m rows per block
#define NSPLIT 16
#define NS (NN / NSPLIT)    // 24 source points per block
#define DEPTH 3
#define SLOTF 4096          // floats per A slot (32 rows x 128 floats)
#define SLOTB 16384         // bytes per A slot

union F16x8u { f16x8 v; pk16x2 h[4]; };

__device__ __forceinline__ void async16(const float* g, float* l) {
    __builtin_amdgcn_global_load_lds((const __attribute__((address_space(1))) void*)g,
                                     (__attribute__((address_space(3))) void*)l, 16, 0, 0);
}

// ---------------------------------------------------------------------------
// Stage 1: block = (b, o-pair p, 32-row m-tile, n-split).
//   part[2p+o, m, c] += sum_{n,k} KB[b,m,n,2p+o,k] * x[b,n,2p+o,c] * Ws[k,c]
// R0 change: x lives in VGPRs (24 packed f16 pairs) instead of a 24 KB xlds
// buffer. LDS = 48 KB A-pipeline only -> 3 blocks/CU (was 2), grid 768 = 3*256
// exactly co-resident, no tail round. Pipeline loop fully unrolled so the x
// register array is statically indexed (no scratch). vmcnt math unchanged:
// at each iteration top, vmcnt<=4 leaves at most stage(i+1)'s 4 loads.
// ---------------------------------------------------------------------------
__global__ __launch_bounds__(256, 3)
void sepconv_stage1(const float* __restrict__ KB, const float* __restrict__ X,
                    const float* __restrict__ Ws, float* __restrict__ part)
{
    extern __shared__ float smem[];
    float* Abuf = smem;                  // DEPTH * 4096 floats (48 KB), nothing else

    const int t    = threadIdx.x;
    const int lane = t & 63;
    const int w    = t >> 6;
    const int l31  = lane & 31;
    const int lh   = lane >> 5;

    const int bid   = blockIdx.x;
    const int mt    = bid % 12;
    const int p     = (bid / 12) & 1;
    const int b     = (bid / 24) & 1;
    const int split = bid / 48;
    const int n0    = split * NS;
    const int cidx  = w * 32 + l31;

    // Ws -> f16 B-fragment registers (this wave's c-subtile)
    f16x8 wsreg[4];
    {
        const float* wp = Ws + (lh * 8) * NC + cidx;
#pragma unroll
        for (int kc = 0; kc < 4; ++kc) {
            f16x8 v;
#pragma unroll
            for (int j = 0; j < 8; ++j)
                v[j] = (_Float16)wp[(kc * 16 + j) * NC];
            wsreg[kc] = v;
        }
    }

    // x slice -> registers: xr[i] = { x[b,n0+i,2p,cidx], x[b,n0+i,2p+1,cidx] } as f16.
    // Same RNE f32->f16 cast as the old xlds path (bit-identical numerics).
    // The converts drain these loads before any stage() is issued, so the
    // manual vmcnt accounting below starts clean.
    pk16x2 xr[NS];
#pragma unroll
    for (int i = 0; i < NS; ++i) {
        const float* xp = X + ((size_t)(b * NN + n0 + i) * NO + 2 * p) * NC + cidx;
        pk16x2 hv;
        hv[0] = (_Float16)xp[0];
        hv[1] = (_Float16)xp[NC];
        xr[i] = hv;
    }

    // per-lane A staging pointers: instr j covers rows 8w+2j(+lh), rotated chunks
    const float* gb[4];
#pragma unroll
    for (int j = 0; j < 4; ++j) {
        const int r = 8 * w + 2 * j + lh;
        const int m = mt * MTW + r;
        gb[j] = KB + ((size_t)(b * NN + m) * NN + n0) * (NO * NK)
                   + p * (2 * NK) + (((l31 + r) & 31) << 2);
    }

    // frag-read byte offsets within a slot (rotation-aware)
    int apos[2][4][2];
#pragma unroll
    for (int o = 0; o < 2; ++o)
#pragma unroll
        for (int kc = 0; kc < 4; ++kc) {
            const int q0 = o * 16 + kc * 4 + lh * 2;
            apos[o][kc][0] = l31 * 512 + ((q0     - l31) & 31) * 16;
            apos[o][kc][1] = l31 * 512 + ((q0 + 1 - l31) & 31) * 16;
        }

    f32x16 acc[2];
#pragma unroll
    for (int o = 0; o < 2; ++o)
#pragma unroll
        for (int r = 0; r < 16; ++r) acc[o][r] = 0.f;

    auto stage = [&](int nl, int slot) {
        float* lb = Abuf + slot * SLOTF + w * 1024;
#pragma unroll
        for (int j = 0; j < 4; ++j)
            async16(gb[j] + nl * (NO * NK), lb + j * 256);
    };

    auto compute = [&](int i, int slot) {
        const char* sb = (const char*)Abuf + slot * SLOTB;
#pragma unroll
        for (int o = 0; o < 2; ++o) {
            const _Float16 xv = xr[i][o];
            f16x8 xh;
#pragma unroll
            for (int j = 0; j < 8; ++j) xh[j] = xv;
#pragma unroll
            for (int kc = 0; kc < 4; ++kc) {
                const f32x4 a0 = *(const f32x4*)(sb + apos[o][kc][0]);
                const f32x4 a1 = *(const f32x4*)(sb + apos[o][kc][1]);
                F16x8u af;
                af.h[0] = __builtin_amdgcn_cvt_pkrtz(a0[0], a0[1]);
                af.h[1] = __builtin_amdgcn_cvt_pkrtz(a0[2], a0[3]);
                af.h[2] = __builtin_amdgcn_cvt_pkrtz(a1[0], a1[1]);
                af.h[3] = __builtin_amdgcn_cvt_pkrtz(a1[2], a1[3]);
                const f16x8 bf = xh * wsreg[kc];
                acc[o] = __builtin_amdgcn_mfma_f32_32x32x16_f16(af.v, bf, acc[o], 0, 0, 0);
            }
        }
    };

    __builtin_amdgcn_sched_barrier(0);    // pin: xr loads/converts before stage(0)
    stage(0, 0);
    stage(1, 1);
    __builtin_amdgcn_sched_barrier(0);

    // Fully unrolled 3-deep pipeline: compile-time i everywhere (xr stays in VGPRs).
    // Invariant at each iteration top after vmcnt<=4: stage(i) complete,
    // at most stage(i+1)'s 4 loads outstanding. Slot (i+2)%3 was last read in
    // compute(i-1); the barrier proves all waves are past it before the DMA lands.
#pragma unroll
    for (int i = 0; i < NS - DEPTH; ++i) {
        __builtin_amdgcn_s_waitcnt(0x0F74);   // vmcnt<=4
        __builtin_amdgcn_s_barrier();         // raw: no vmcnt(0) drain
        __builtin_amdgcn_sched_barrier(0);
        stage(i + 2, (i + 2) % DEPTH);
        __builtin_amdgcn_sched_barrier(0);
        compute(i, i % DEPTH);
    }
    // tail: i = NS-3, NS-2, NS-1
    __builtin_amdgcn_s_waitcnt(0x0F74); __builtin_amdgcn_s_barrier();
    __builtin_amdgcn_sched_barrier(0);
    stage(NS - 1, (NS - 1) % DEPTH);
    __builtin_amdgcn_sched_barrier(0);
    compute(NS - 3, (NS - 3) % DEPTH);
    __builtin_amdgcn_s_waitcnt(0x0F74); __builtin_amdgcn_s_barrier();
    __builtin_amdgcn_sched_barrier(0);
    compute(NS - 2, (NS - 2) % DEPTH);
    __builtin_amdgcn_s_waitcnt(0x0F70); __builtin_amdgcn_s_barrier();
    __builtin_amdgcn_sched_barrier(0);
    compute(NS - 1, (NS - 1) % DEPTH);

    // epilogue: fp32 partials [split][b][o][m][c]
    float* pb = part + ((size_t)(split * NB + b) * NO + 2 * p) * (NN * NC)
                     + (size_t)(mt * MTW) * NC + cidx;
#pragma unroll
    for (int o = 0; o < 2; ++o)
#pragma unroll
        for (int r = 0; r < 16; ++r) {
            const int ml = (r & 3) + 8 * (r >> 2) + 4 * lh;   // C/D row map (m74/m101)
            pb[(size_t)o * NN * NC + ml * NC] = acc[o][r];
        }
}

// ---------------------------------------------------------------------------
// Stage 2: reduce splits, fiber/rot mixing + bias (unchanged — isolates the
// stage1 occupancy experiment).
// ---------------------------------------------------------------------------
__global__ __launch_bounds__(256)
void sepconv_stage2(const float* __restrict__ part, const float* __restrict__ fiber,
                    const float* __restrict__ Wr, const float* __restrict__ bias,
                    float* __restrict__ out, int nsplit)
{
    const int bid = blockIdx.x;
    const int b = bid / NN;
    const int m = bid % NN;
    const int t = threadIdx.x;
    const int c = t & 127;
    const int g = t >> 7;

    float rot[8];
#pragma unroll
    for (int i = 0; i < 8; ++i) rot[i] = 0.f;
    for (int k = 0; k < NK; ++k) {
        const float wv = Wr[k * NC + c];
#pragma unroll
        for (int q = 0; q < 2; ++q)
#pragma unroll
            for (int oo = 0; oo < 4; ++oo)
                rot[q * 4 + oo] += fiber[((2 * g + q) * NO + oo) * NK + k] * wv;
    }

    float y1[4];
#pragma unroll
    for (int oo = 0; oo < 4; ++oo) {
        float s = 0.f;
        for (int sp = 0; sp < nsplit; ++sp)
            s += part[((size_t)(sp * NB + b) * NO + oo) * (NN * NC) + m * NC + c];
        y1[oo] = s;
    }

    const float bv = bias[c];
#pragma unroll
    for (int q = 0; q < 2; ++q) {
        float v = bv;
#pragma unroll
        for (int oo = 0; oo < 4; ++oo) v += y1[oo] * rot[q * 4 + oo];
        out[((b * NN + m) * NO + (2 * g + q)) * NC + c] = v;
    }
}

extern "C" void kernel_launch(void* const* d_in, const int* in_sizes, int n_in,
                              void* d_out, int out_size, void* d_ws, size_t ws_size,
                              hipStream_t stream)
{
    const float* X    = (const float*)d_in[0];
    const float* KB   = (const float*)d_in[1];
    const float* FB   = (const float*)d_in[2];
    const float* Ws   = (const float*)d_in[3];
    const float* Wr   = (const float*)d_in[4];
    const float* bias = (const float*)d_in[5];
    float* out  = (float*)d_out;
    float* part = (float*)d_ws;   // 16 * 1.57 MB = 25 MB of fp32 partials

    const size_t lds = (size_t)DEPTH * SLOTF * sizeof(float);  // 49152 B -> 3 blocks/CU

    sepconv_stage1<<<dim3(12 * 2 * NB * NSPLIT), dim3(256), lds, stream>>>(KB, X, Ws, part);
    sepconv_stage2<<<dim3(NB * NN), dim3(256), 0, stream>>>(part, FB, Wr, bias, out, NSPLIT);
}